// Round 1
// baseline (720.814 us; speedup 1.0000x reference)
//
#include <hip/hip_runtime.h>
#include <math.h>
#include <stdint.h>

#define EPS 1e-5f

typedef int v4i __attribute__((ext_vector_type(4)));

__device__ __forceinline__ void glds16(const void* g, void* l) {
  __builtin_amdgcn_global_load_lds(
      (const __attribute__((address_space(1))) void*)g,
      (__attribute__((address_space(3))) void*)l, 16, 0, 0);
}

__device__ __forceinline__ signed char q8(float f, float xs) {
  float r = rintf(f * xs);
  r = fminf(fmaxf(r, -128.f), 127.f);
  return (signed char)(int)r;
}

// ---------------- weight abs-sum (hierarchical, 1 atomic/block) ----------------
__global__ __launch_bounds__(256) void absum_kernel(const float* __restrict__ w,
                                                    long n4, float* __restrict__ out) {
  long i = (long)blockIdx.x * 256 + threadIdx.x;
  long stride = (long)gridDim.x * 256;
  const float4* w4 = (const float4*)w;
  float s = 0.f;
  for (; i < n4; i += stride) {
    float4 v = w4[i];
    s += fabsf(v.x) + fabsf(v.y) + fabsf(v.z) + fabsf(v.w);
  }
  for (int off = 32; off; off >>= 1) s += __shfl_down(s, off);
  __shared__ float sb[4];
  int lane = threadIdx.x & 63, wid = threadIdx.x >> 6;
  if (lane == 0) sb[wid] = s;
  __syncthreads();
  if (threadIdx.x == 0) atomicAdd(out, sb[0] + sb[1] + sb[2] + sb[3]);
}

// ---------------- ternarize weights: t = clip(round(w/ws),-1,1) int8 ----------------
__global__ __launch_bounds__(256) void ternarize_kernel(const float* __restrict__ w,
                                                        signed char* __restrict__ t, long n4,
                                                        const float* __restrict__ sum_ptr,
                                                        float inv_n) {
  float ws = sum_ptr[0] * inv_n + EPS;
  long i = (long)blockIdx.x * 256 + threadIdx.x;
  long stride = (long)gridDim.x * 256;
  const float4* w4 = (const float4*)w;
  char4* t4 = (char4*)t;
  for (; i < n4; i += stride) {
    float4 v = w4[i];
    char4 c;
    c.x = (signed char)(int)fminf(fmaxf(rintf(v.x / ws), -1.f), 1.f);
    c.y = (signed char)(int)fminf(fmaxf(rintf(v.y / ws), -1.f), 1.f);
    c.z = (signed char)(int)fminf(fmaxf(rintf(v.z / ws), -1.f), 1.f);
    c.w = (signed char)(int)fminf(fmaxf(rintf(v.w / ws), -1.f), 1.f);
    t4[i] = c;
  }
}

// ---------------- LN1: write xn fp32 + per-row absmax ----------------
__global__ __launch_bounds__(256) void ln_rowmax_kernel(const float* __restrict__ x,
                                                        const float* __restrict__ w,
                                                        const float* __restrict__ b,
                                                        float* __restrict__ xn,
                                                        float* __restrict__ rowmax) {
  int m = blockIdx.x;
  int tid = threadIdx.x, lane = tid & 63, wid = tid >> 6;
  __shared__ float sb[4];
  float4 v = ((const float4*)(x + (long)m * 1024))[tid];
  float s = v.x + v.y + v.z + v.w;
  for (int off = 32; off; off >>= 1) s += __shfl_down(s, off);
  if (lane == 0) sb[wid] = s;
  __syncthreads();
  float mean = (sb[0] + sb[1] + sb[2] + sb[3]) * (1.f / 1024.f);
  __syncthreads();
  float dx = v.x - mean, dy = v.y - mean, dz = v.z - mean, dw = v.w - mean;
  float ss = dx * dx + dy * dy + dz * dz + dw * dw;
  for (int off = 32; off; off >>= 1) ss += __shfl_down(ss, off);
  if (lane == 0) sb[wid] = ss;
  __syncthreads();
  float rstd = rsqrtf((sb[0] + sb[1] + sb[2] + sb[3]) * (1.f / 1024.f) + EPS);
  __syncthreads();
  float4 wv = ((const float4*)w)[tid];
  float4 bv = ((const float4*)b)[tid];
  float4 o;
  o.x = dx * rstd * wv.x + bv.x;
  o.y = dy * rstd * wv.y + bv.y;
  o.z = dz * rstd * wv.z + bv.z;
  o.w = dw * rstd * wv.w + bv.w;
  ((float4*)(xn + (long)m * 1024))[tid] = o;
  float mx = fmaxf(fmaxf(fabsf(o.x), fabsf(o.y)), fmaxf(fabsf(o.z), fabsf(o.w)));
  for (int off = 32; off; off >>= 1) mx = fmaxf(mx, __shfl_down(mx, off));
  if (lane == 0) sb[wid] = mx;
  __syncthreads();
  if (tid == 0) rowmax[m] = fmaxf(fmaxf(sb[0], sb[1]), fmaxf(sb[2], sb[3]));
}

// ---------------- per-token combined scale: xs1 = 127/cmax, s1 = ws_g*cmax/127 ----------------
__global__ __launch_bounds__(256) void scale1_kernel(const float* __restrict__ rowmax,
                                                     const int* __restrict__ is0,
                                                     const int* __restrict__ is1,
                                                     const int* __restrict__ iv,
                                                     const float* __restrict__ sums,
                                                     float* __restrict__ xs1,
                                                     float* __restrict__ s1) {
  int t = blockIdx.x * 256 + threadIdx.x;
  if (t >= 8192) return;
  int b = t >> 8, l = t & 255;
  const float* rm = rowmax + b * 256;
  float c = rm[l];
  for (int j = 0; j < 3; ++j) c = fmaxf(c, rm[is0[l * 3 + j]]);
  for (int j = 0; j < 3; ++j) c = fmaxf(c, rm[is1[l * 3 + j]]);
  for (int j = 0; j < 8; ++j) c = fmaxf(c, rm[iv[l * 8 + j]]);
  c = fmaxf(c, EPS);
  xs1[t] = 127.f / c;
  s1[t] = (sums[0] * (1.f / 15728640.f) + EPS) * c * (1.f / 127.f);
}

// ---------------- quantize gathered combined matrix to int8 [8192,15360] ----------------
__global__ __launch_bounds__(256) void quantA_kernel(const float* __restrict__ xn,
                                                     const int* __restrict__ is0,
                                                     const int* __restrict__ is1,
                                                     const int* __restrict__ iv,
                                                     const float* __restrict__ xs1,
                                                     signed char* __restrict__ Aq) {
  int slot = blockIdx.x;  // 0..14
  int m = blockIdx.y;     // 0..8191
  int b = m >> 8, l = m & 255;
  int src;
  if (slot == 0) src = l;
  else if (slot < 4) src = is0[l * 3 + slot - 1];
  else if (slot < 7) src = is1[l * 3 + slot - 4];
  else src = iv[l * 8 + slot - 7];
  float xs = xs1[m];
  float4 v = ((const float4*)(xn + ((long)b * 256 + src) * 1024))[threadIdx.x];
  char4 c;
  c.x = q8(v.x, xs); c.y = q8(v.y, xs); c.z = q8(v.z, xs); c.w = q8(v.w, xs);
  *(char4*)&Aq[(long)m * 15360 + slot * 1024 + threadIdx.x * 4] = c;
}

// ---------------- fused LN2 + quantize to int8 ----------------
__global__ __launch_bounds__(256) void ln_quant_kernel(const float* __restrict__ x,
                                                       const float* __restrict__ w,
                                                       const float* __restrict__ bb,
                                                       signed char* __restrict__ q,
                                                       float* __restrict__ srow,
                                                       const float* __restrict__ sum_ptr,
                                                       float inv_n) {
  int m = blockIdx.x;
  int tid = threadIdx.x, lane = tid & 63, wid = tid >> 6;
  __shared__ float sb[4];
  float4 v = ((const float4*)(x + (long)m * 1024))[tid];
  float s = v.x + v.y + v.z + v.w;
  for (int off = 32; off; off >>= 1) s += __shfl_down(s, off);
  if (lane == 0) sb[wid] = s;
  __syncthreads();
  float mean = (sb[0] + sb[1] + sb[2] + sb[3]) * (1.f / 1024.f);
  __syncthreads();
  float dx = v.x - mean, dy = v.y - mean, dz = v.z - mean, dw = v.w - mean;
  float ss = dx * dx + dy * dy + dz * dz + dw * dw;
  for (int off = 32; off; off >>= 1) ss += __shfl_down(ss, off);
  if (lane == 0) sb[wid] = ss;
  __syncthreads();
  float rstd = rsqrtf((sb[0] + sb[1] + sb[2] + sb[3]) * (1.f / 1024.f) + EPS);
  __syncthreads();
  float4 wv = ((const float4*)w)[tid];
  float4 bv = ((const float4*)bb)[tid];
  float nx = dx * rstd * wv.x + bv.x;
  float ny = dy * rstd * wv.y + bv.y;
  float nz = dz * rstd * wv.z + bv.z;
  float nw = dw * rstd * wv.w + bv.w;
  float mx = fmaxf(fmaxf(fabsf(nx), fabsf(ny)), fmaxf(fabsf(nz), fabsf(nw)));
  for (int off = 32; off; off >>= 1) mx = fmaxf(mx, __shfl_down(mx, off));
  if (lane == 0) sb[wid] = mx;
  __syncthreads();
  float rmax = fmaxf(fmaxf(fmaxf(sb[0], sb[1]), fmaxf(sb[2], sb[3])), EPS);
  float xs = 127.f / rmax;
  char4 c;
  c.x = q8(nx, xs); c.y = q8(ny, xs); c.z = q8(nz, xs); c.w = q8(nw, xs);
  *(char4*)&q[(long)m * 1024 + tid * 4] = c;
  if (tid == 0) srow[m] = (sum_ptr[0] * inv_n + EPS) * rmax * (1.f / 127.f);
}

// ---------------- row quantize [8192,4096] fp32 -> int8 ----------------
__global__ __launch_bounds__(256) void rowquant4k_kernel(const float* __restrict__ g,
                                                         signed char* __restrict__ q,
                                                         float* __restrict__ srow,
                                                         const float* __restrict__ sum_ptr,
                                                         float inv_n) {
  int m = blockIdx.x;
  int tid = threadIdx.x, lane = tid & 63, wid = tid >> 6;
  __shared__ float sb[4];
  const float4* gr = (const float4*)(g + (long)m * 4096);
  float4 vals[4];
  float mx = 0.f;
#pragma unroll
  for (int i = 0; i < 4; ++i) {
    vals[i] = gr[tid + i * 256];
    mx = fmaxf(mx, fmaxf(fmaxf(fabsf(vals[i].x), fabsf(vals[i].y)),
                         fmaxf(fabsf(vals[i].z), fabsf(vals[i].w))));
  }
  for (int off = 32; off; off >>= 1) mx = fmaxf(mx, __shfl_down(mx, off));
  if (lane == 0) sb[wid] = mx;
  __syncthreads();
  float rmax = fmaxf(fmaxf(fmaxf(sb[0], sb[1]), fmaxf(sb[2], sb[3])), EPS);
  float xs = 127.f / rmax;
#pragma unroll
  for (int i = 0; i < 4; ++i) {
    char4 c;
    c.x = q8(vals[i].x, xs); c.y = q8(vals[i].y, xs);
    c.z = q8(vals[i].z, xs); c.w = q8(vals[i].w, xs);
    *(char4*)&q[(long)m * 4096 + (tid + i * 256) * 4] = c;
  }
  if (tid == 0) srow[m] = (sum_ptr[0] * inv_n + EPS) * rmax * (1.f / 127.f);
}

// ---------------- int8 GEMM, m97 structure: 128x128 tile, BK=128, 16x16x64 MFMA ----------------
// A: [M,K] int8 row-major; Bw: [N,K] int8 row-major (B^T layout).
// mode 0: out[m,n] = aux[m,n] + scale[m]*acc   mode 1: out[m,n] = gelu(scale[m]*acc)
__global__ __launch_bounds__(256) void gemm_i8(const signed char* __restrict__ A,
                                               const signed char* __restrict__ Bw,
                                               float* __restrict__ out,
                                               const float* __restrict__ scale,
                                               const float* __restrict__ aux,
                                               int N, int K, int mode) {
  __shared__ __align__(16) signed char As[128 * 128];
  __shared__ __align__(16) signed char Bs[128 * 128];
  const int tid = threadIdx.x;
  const int lane = tid & 63, wave = tid >> 6;
  const int wm = wave & 1, wn = wave >> 1;
  const long m0 = (long)blockIdx.y * 128;
  const long n0 = (long)blockIdx.x * 128;
  const signed char* Abase = A + m0 * K;
  const signed char* Bbase = Bw + n0 * K;

  v4i acc[4][4] = {};

  const int nkt = K >> 7;
  for (int kt = 0; kt < nkt; ++kt) {
    const long k0 = (long)kt << 7;
#pragma unroll
    for (int i = 0; i < 4; ++i) {
      int cb = wave * 64 + i * 256;        // wave-uniform chunk base
      int c = cb + lane;                   // per-lane chunk
      long row = c >> 3;
      long colb = (long)(c & 7) << 4;
      glds16(Abase + row * K + k0 + colb, &As[cb * 16]);
      glds16(Bbase + row * K + k0 + colb, &Bs[cb * 16]);
    }
    __syncthreads();
#pragma unroll
    for (int ks = 0; ks < 2; ++ks) {
      const int koff = ks * 64 + (lane >> 4) * 16;
      v4i af[4], bf[4];
#pragma unroll
      for (int mi = 0; mi < 4; ++mi)
        af[mi] = *(const v4i*)&As[(wm * 64 + mi * 16 + (lane & 15)) * 128 + koff];
#pragma unroll
      for (int ni = 0; ni < 4; ++ni)
        bf[ni] = *(const v4i*)&Bs[(wn * 64 + ni * 16 + (lane & 15)) * 128 + koff];
#pragma unroll
      for (int mi = 0; mi < 4; ++mi)
#pragma unroll
        for (int ni = 0; ni < 4; ++ni)
          acc[mi][ni] = __builtin_amdgcn_mfma_i32_16x16x64_i8(af[mi], bf[ni], acc[mi][ni], 0, 0, 0);
    }
    __syncthreads();
  }

  // epilogue: C/D layout col=lane&15, row=(lane>>4)*4+reg (dtype-independent, m89/m121)
#pragma unroll
  for (int mi = 0; mi < 4; ++mi) {
#pragma unroll
    for (int r = 0; r < 4; ++r) {
      long m = m0 + wm * 64 + mi * 16 + (lane >> 4) * 4 + r;
      float sm = scale[m];
      float* outrow = out + m * N;
      const float* auxrow = aux ? aux + m * N : nullptr;
#pragma unroll
      for (int ni = 0; ni < 4; ++ni) {
        long n = n0 + wn * 64 + ni * 16 + (lane & 15);
        float v = sm * (float)acc[mi][ni][r];
        if (mode == 0) {
          outrow[n] = auxrow[n] + v;
        } else {
          outrow[n] = 0.5f * v * (1.f + erff(v * 0.70710678118654752f));
        }
      }
    }
  }
}

extern "C" void kernel_launch(void* const* d_in, const int* in_sizes, int n_in,
                              void* d_out, int out_size, void* d_ws, size_t ws_size,
                              hipStream_t stream) {
  const float* x    = (const float*)d_in[0];
  const float* ln1w = (const float*)d_in[1];
  const float* ln1b = (const float*)d_in[2];
  const float* ln2w = (const float*)d_in[3];
  const float* ln2b = (const float*)d_in[4];
  const float* Wg   = (const float*)d_in[5];
  const float* W1   = (const float*)d_in[6];
  const float* W2   = (const float*)d_in[7];
  const int* is0    = (const int*)d_in[8];
  const int* is1    = (const int*)d_in[9];
  const int* iv     = (const int*)d_in[10];
  float* out = (float*)d_out;

  // workspace layout (all 256B-aligned, ~224 MB):
  char* ws = (char*)d_ws;
  float* sums = (float*)ws;                                   // 3 floats (+pad)
  signed char* t_g = (signed char*)(ws + 256);                // 15,728,640
  signed char* t_1 = t_g + 15728640;                          //  4,194,304
  signed char* t_2 = t_1 + 4194304;                           //  4,194,304
  float* rowmax1 = (float*)(t_2 + 4194304);                   // 32,768 B
  float* xs1 = rowmax1 + 8192;
  float* s1  = xs1 + 8192;
  float* s2  = s1 + 8192;
  float* s3  = s2 + 8192;
  float* xag = s3 + 8192;                                     // 33,554,432 B
  signed char* hq = (signed char*)(xag + 8388608);            //  8,388,608 B
  float* xn = (float*)(hq + 8388608);                         // 33,554,432 B
  signed char* q3 = (signed char*)xn;                         // reuse (xn dead after quantA)
  signed char* Aq = (signed char*)(xn + 8388608);             // 125.8 MB
  float* gg = (float*)Aq;                                     // reuse as 134.2 MB (Aq dead after GEMM1)

  hipMemsetAsync(sums, 0, 64, stream);
  absum_kernel<<<512, 256, 0, stream>>>(Wg, 15728640 / 4, &sums[0]);
  absum_kernel<<<256, 256, 0, stream>>>(W1, 4194304 / 4, &sums[1]);
  absum_kernel<<<256, 256, 0, stream>>>(W2, 4194304 / 4, &sums[2]);
  ternarize_kernel<<<1024, 256, 0, stream>>>(Wg, t_g, 15728640 / 4, &sums[0], 1.f / 15728640.f);
  ternarize_kernel<<<512, 256, 0, stream>>>(W1, t_1, 4194304 / 4, &sums[1], 1.f / 4194304.f);
  ternarize_kernel<<<512, 256, 0, stream>>>(W2, t_2, 4194304 / 4, &sums[2], 1.f / 4194304.f);
  ln_rowmax_kernel<<<8192, 256, 0, stream>>>(x, ln1w, ln1b, xn, rowmax1);
  scale1_kernel<<<32, 256, 0, stream>>>(rowmax1, is0, is1, iv, sums, xs1, s1);
  quantA_kernel<<<dim3(15, 8192), 256, 0, stream>>>(xn, is0, is1, iv, xs1, Aq);
  gemm_i8<<<dim3(8, 64), 256, 0, stream>>>(Aq, t_g, xag, s1, x, 1024, 15360, 0);
  ln_quant_kernel<<<8192, 256, 0, stream>>>(xag, ln2w, ln2b, hq, s2, &sums[1], 1.f / 4194304.f);
  gemm_i8<<<dim3(32, 64), 256, 0, stream>>>(hq, t_1, gg, s2, nullptr, 4096, 1024, 1);
  rowquant4k_kernel<<<8192, 256, 0, stream>>>(gg, q3, s3, &sums[2], 1.f / 4194304.f);
  gemm_i8<<<dim3(8, 64), 256, 0, stream>>>(q3, t_2, out, s3, xag, 1024, 4096, 0);
}

// Round 2
// 681.713 us; speedup vs baseline: 1.0574x; 1.0574x over previous
//
#include <hip/hip_runtime.h>
#include <math.h>
#include <stdint.h>

#define EPS 1e-5f

typedef int v4i __attribute__((ext_vector_type(4)));

__device__ __forceinline__ void glds16(const void* g, void* l) {
  __builtin_amdgcn_global_load_lds(
      (const __attribute__((address_space(1))) void*)g,
      (__attribute__((address_space(3))) void*)l, 16, 0, 0);
}

__device__ __forceinline__ signed char q8(float f, float xs) {
  float r = rintf(f * xs);
  r = fminf(fmaxf(r, -128.f), 127.f);
  return (signed char)(int)r;
}

// ---------------- weight abs-sum (hierarchical, 1 atomic/block) ----------------
__global__ __launch_bounds__(256) void absum_kernel(const float* __restrict__ w,
                                                    long n4, float* __restrict__ out) {
  long i = (long)blockIdx.x * 256 + threadIdx.x;
  long stride = (long)gridDim.x * 256;
  const float4* w4 = (const float4*)w;
  float s = 0.f;
  for (; i < n4; i += stride) {
    float4 v = w4[i];
    s += fabsf(v.x) + fabsf(v.y) + fabsf(v.z) + fabsf(v.w);
  }
  for (int off = 32; off; off >>= 1) s += __shfl_down(s, off);
  __shared__ float sb[4];
  int lane = threadIdx.x & 63, wid = threadIdx.x >> 6;
  if (lane == 0) sb[wid] = s;
  __syncthreads();
  if (threadIdx.x == 0) atomicAdd(out, sb[0] + sb[1] + sb[2] + sb[3]);
}

// ---------------- ternarize weights: t = clip(round(w/ws),-1,1) int8 ----------------
__global__ __launch_bounds__(256) void ternarize_kernel(const float* __restrict__ w,
                                                        signed char* __restrict__ t, long n4,
                                                        const float* __restrict__ sum_ptr,
                                                        float inv_n) {
  float ws = sum_ptr[0] * inv_n + EPS;
  long i = (long)blockIdx.x * 256 + threadIdx.x;
  long stride = (long)gridDim.x * 256;
  const float4* w4 = (const float4*)w;
  char4* t4 = (char4*)t;
  for (; i < n4; i += stride) {
    float4 v = w4[i];
    char4 c;
    c.x = (signed char)(int)fminf(fmaxf(rintf(v.x / ws), -1.f), 1.f);
    c.y = (signed char)(int)fminf(fmaxf(rintf(v.y / ws), -1.f), 1.f);
    c.z = (signed char)(int)fminf(fmaxf(rintf(v.z / ws), -1.f), 1.f);
    c.w = (signed char)(int)fminf(fmaxf(rintf(v.w / ws), -1.f), 1.f);
    t4[i] = c;
  }
}

// ---------------- LN1: write xn fp32 + per-row absmax ----------------
__global__ __launch_bounds__(256) void ln_rowmax_kernel(const float* __restrict__ x,
                                                        const float* __restrict__ w,
                                                        const float* __restrict__ b,
                                                        float* __restrict__ xn,
                                                        float* __restrict__ rowmax) {
  int m = blockIdx.x;
  int tid = threadIdx.x, lane = tid & 63, wid = tid >> 6;
  __shared__ float sb[4];
  float4 v = ((const float4*)(x + (long)m * 1024))[tid];
  float s = v.x + v.y + v.z + v.w;
  for (int off = 32; off; off >>= 1) s += __shfl_down(s, off);
  if (lane == 0) sb[wid] = s;
  __syncthreads();
  float mean = (sb[0] + sb[1] + sb[2] + sb[3]) * (1.f / 1024.f);
  __syncthreads();
  float dx = v.x - mean, dy = v.y - mean, dz = v.z - mean, dw = v.w - mean;
  float ss = dx * dx + dy * dy + dz * dz + dw * dw;
  for (int off = 32; off; off >>= 1) ss += __shfl_down(ss, off);
  if (lane == 0) sb[wid] = ss;
  __syncthreads();
  float rstd = rsqrtf((sb[0] + sb[1] + sb[2] + sb[3]) * (1.f / 1024.f) + EPS);
  __syncthreads();
  float4 wv = ((const float4*)w)[tid];
  float4 bv = ((const float4*)b)[tid];
  float4 o;
  o.x = dx * rstd * wv.x + bv.x;
  o.y = dy * rstd * wv.y + bv.y;
  o.z = dz * rstd * wv.z + bv.z;
  o.w = dw * rstd * wv.w + bv.w;
  ((float4*)(xn + (long)m * 1024))[tid] = o;
  float mx = fmaxf(fmaxf(fabsf(o.x), fabsf(o.y)), fmaxf(fabsf(o.z), fabsf(o.w)));
  for (int off = 32; off; off >>= 1) mx = fmaxf(mx, __shfl_down(mx, off));
  if (lane == 0) sb[wid] = mx;
  __syncthreads();
  if (tid == 0) rowmax[m] = fmaxf(fmaxf(sb[0], sb[1]), fmaxf(sb[2], sb[3]));
}

// ---------------- per-token combined scale: xs1 = 127/cmax, s1 = ws_g*cmax/127 ----------------
__global__ __launch_bounds__(256) void scale1_kernel(const float* __restrict__ rowmax,
                                                     const int* __restrict__ is0,
                                                     const int* __restrict__ is1,
                                                     const int* __restrict__ iv,
                                                     const float* __restrict__ sums,
                                                     float* __restrict__ xs1,
                                                     float* __restrict__ s1) {
  int t = blockIdx.x * 256 + threadIdx.x;
  if (t >= 8192) return;
  int b = t >> 8, l = t & 255;
  const float* rm = rowmax + b * 256;
  float c = rm[l];
  for (int j = 0; j < 3; ++j) c = fmaxf(c, rm[is0[l * 3 + j]]);
  for (int j = 0; j < 3; ++j) c = fmaxf(c, rm[is1[l * 3 + j]]);
  for (int j = 0; j < 8; ++j) c = fmaxf(c, rm[iv[l * 8 + j]]);
  c = fmaxf(c, EPS);
  xs1[t] = 127.f / c;
  s1[t] = (sums[0] * (1.f / 15728640.f) + EPS) * c * (1.f / 127.f);
}

// ---------------- quantize gathered combined matrix to int8 [8192,15360] ----------------
__global__ __launch_bounds__(256) void quantA_kernel(const float* __restrict__ xn,
                                                     const int* __restrict__ is0,
                                                     const int* __restrict__ is1,
                                                     const int* __restrict__ iv,
                                                     const float* __restrict__ xs1,
                                                     signed char* __restrict__ Aq) {
  int slot = blockIdx.x;  // 0..14
  int m = blockIdx.y;     // 0..8191
  int b = m >> 8, l = m & 255;
  int src;
  if (slot == 0) src = l;
  else if (slot < 4) src = is0[l * 3 + slot - 1];
  else if (slot < 7) src = is1[l * 3 + slot - 4];
  else src = iv[l * 8 + slot - 7];
  float xs = xs1[m];
  float4 v = ((const float4*)(xn + ((long)b * 256 + src) * 1024))[threadIdx.x];
  char4 c;
  c.x = q8(v.x, xs); c.y = q8(v.y, xs); c.z = q8(v.z, xs); c.w = q8(v.w, xs);
  *(char4*)&Aq[(long)m * 15360 + slot * 1024 + threadIdx.x * 4] = c;
}

// ---------------- fused LN2 + quantize to int8 ----------------
__global__ __launch_bounds__(256) void ln_quant_kernel(const float* __restrict__ x,
                                                       const float* __restrict__ w,
                                                       const float* __restrict__ bb,
                                                       signed char* __restrict__ q,
                                                       float* __restrict__ srow,
                                                       const float* __restrict__ sum_ptr,
                                                       float inv_n) {
  int m = blockIdx.x;
  int tid = threadIdx.x, lane = tid & 63, wid = tid >> 6;
  __shared__ float sb[4];
  float4 v = ((const float4*)(x + (long)m * 1024))[tid];
  float s = v.x + v.y + v.z + v.w;
  for (int off = 32; off; off >>= 1) s += __shfl_down(s, off);
  if (lane == 0) sb[wid] = s;
  __syncthreads();
  float mean = (sb[0] + sb[1] + sb[2] + sb[3]) * (1.f / 1024.f);
  __syncthreads();
  float dx = v.x - mean, dy = v.y - mean, dz = v.z - mean, dw = v.w - mean;
  float ss = dx * dx + dy * dy + dz * dz + dw * dw;
  for (int off = 32; off; off >>= 1) ss += __shfl_down(ss, off);
  if (lane == 0) sb[wid] = ss;
  __syncthreads();
  float rstd = rsqrtf((sb[0] + sb[1] + sb[2] + sb[3]) * (1.f / 1024.f) + EPS);
  __syncthreads();
  float4 wv = ((const float4*)w)[tid];
  float4 bv = ((const float4*)bb)[tid];
  float nx = dx * rstd * wv.x + bv.x;
  float ny = dy * rstd * wv.y + bv.y;
  float nz = dz * rstd * wv.z + bv.z;
  float nw = dw * rstd * wv.w + bv.w;
  float mx = fmaxf(fmaxf(fabsf(nx), fabsf(ny)), fmaxf(fabsf(nz), fabsf(nw)));
  for (int off = 32; off; off >>= 1) mx = fmaxf(mx, __shfl_down(mx, off));
  if (lane == 0) sb[wid] = mx;
  __syncthreads();
  float rmax = fmaxf(fmaxf(fmaxf(sb[0], sb[1]), fmaxf(sb[2], sb[3])), EPS);
  float xs = 127.f / rmax;
  char4 c;
  c.x = q8(nx, xs); c.y = q8(ny, xs); c.z = q8(nz, xs); c.w = q8(nw, xs);
  *(char4*)&q[(long)m * 1024 + tid * 4] = c;
  if (tid == 0) srow[m] = (sum_ptr[0] * inv_n + EPS) * rmax * (1.f / 127.f);
}

// ---------------- row quantize [8192,4096] fp32 -> int8 ----------------
__global__ __launch_bounds__(256) void rowquant4k_kernel(const float* __restrict__ g,
                                                         signed char* __restrict__ q,
                                                         float* __restrict__ srow,
                                                         const float* __restrict__ sum_ptr,
                                                         float inv_n) {
  int m = blockIdx.x;
  int tid = threadIdx.x, lane = tid & 63, wid = tid >> 6;
  __shared__ float sb[4];
  const float4* gr = (const float4*)(g + (long)m * 4096);
  float4 vals[4];
  float mx = 0.f;
#pragma unroll
  for (int i = 0; i < 4; ++i) {
    vals[i] = gr[tid + i * 256];
    mx = fmaxf(mx, fmaxf(fmaxf(fabsf(vals[i].x), fabsf(vals[i].y)),
                         fmaxf(fabsf(vals[i].z), fabsf(vals[i].w))));
  }
  for (int off = 32; off; off >>= 1) mx = fmaxf(mx, __shfl_down(mx, off));
  if (lane == 0) sb[wid] = mx;
  __syncthreads();
  float rmax = fmaxf(fmaxf(fmaxf(sb[0], sb[1]), fmaxf(sb[2], sb[3])), EPS);
  float xs = 127.f / rmax;
#pragma unroll
  for (int i = 0; i < 4; ++i) {
    char4 c;
    c.x = q8(vals[i].x, xs); c.y = q8(vals[i].y, xs);
    c.z = q8(vals[i].z, xs); c.w = q8(vals[i].w, xs);
    *(char4*)&q[(long)m * 4096 + (tid + i * 256) * 4] = c;
  }
  if (tid == 0) srow[m] = (sum_ptr[0] * inv_n + EPS) * rmax * (1.f / 127.f);
}

// ---------------- int8 GEMM, 128x128 tile, BK=128, 16x16x64 MFMA ----------------
// LDS layout is XOR-swizzled: logical (row, 16B-block j) lives at
// row*128 + (j ^ (row&7))*16. Staging permutes the global source block index
// (coalescing unchanged: permutation stays within each 128B row segment);
// fragment reads land 2 lanes/bank (2-way = free, m136) instead of 8-way.
// A: [M,K] int8 row-major; Bw: [N,K] int8 row-major (B^T layout).
// mode 0: out[m,n] = aux[m,n] + scale[m]*acc   mode 1: out[m,n] = gelu(scale[m]*acc)
__global__ __launch_bounds__(256) void gemm_i8(const signed char* __restrict__ A,
                                               const signed char* __restrict__ Bw,
                                               float* __restrict__ out,
                                               const float* __restrict__ scale,
                                               const float* __restrict__ aux,
                                               int N, int K, int mode) {
  __shared__ __align__(16) signed char As[128 * 128];
  __shared__ __align__(16) signed char Bs[128 * 128];
  const int tid = threadIdx.x;
  const int lane = tid & 63, wave = tid >> 6;
  const int wm = wave & 1, wn = wave >> 1;
  const long m0 = (long)blockIdx.y * 128;
  const long n0 = (long)blockIdx.x * 128;
  const signed char* Abase = A + m0 * K;
  const signed char* Bbase = Bw + n0 * K;

  v4i acc[4][4] = {};

  // staging address pre-compute (swizzled source block)
  const int r15 = lane & 15;
  const int quad = lane >> 4;   // 0..3
  const int sw = lane & 7;      // = row&7 for all fragment rows

  const int nkt = K >> 7;
  for (int kt = 0; kt < nkt; ++kt) {
    const long k0 = (long)kt << 7;
#pragma unroll
    for (int i = 0; i < 4; ++i) {
      int cb = wave * 64 + i * 256;        // wave-uniform chunk base
      int c = cb + lane;                   // per-lane chunk
      long row = c >> 3;
      int blk = (c & 7) ^ ((c >> 3) & 7);  // XOR swizzle of source block
      long colb = (long)blk << 4;
      glds16(Abase + row * K + k0 + colb, &As[cb * 16]);
      glds16(Bbase + row * K + k0 + colb, &Bs[cb * 16]);
    }
    __syncthreads();
#pragma unroll
    for (int ks = 0; ks < 2; ++ks) {
      const int blkb = (ks << 2) + quad;   // logical 16B block index (0..7)
      const int coff = (blkb ^ sw) << 4;   // swizzled byte offset within row
      v4i af[4], bf[4];
#pragma unroll
      for (int mi = 0; mi < 4; ++mi)
        af[mi] = *(const v4i*)&As[(wm * 64 + mi * 16 + r15) * 128 + coff];
#pragma unroll
      for (int ni = 0; ni < 4; ++ni)
        bf[ni] = *(const v4i*)&Bs[(wn * 64 + ni * 16 + r15) * 128 + coff];
#pragma unroll
      for (int mi = 0; mi < 4; ++mi)
#pragma unroll
        for (int ni = 0; ni < 4; ++ni)
          acc[mi][ni] = __builtin_amdgcn_mfma_i32_16x16x64_i8(af[mi], bf[ni], acc[mi][ni], 0, 0, 0);
    }
    __syncthreads();
  }

  // epilogue: C/D layout col=lane&15, row=(lane>>4)*4+reg (dtype-independent, m89/m121)
#pragma unroll
  for (int mi = 0; mi < 4; ++mi) {
#pragma unroll
    for (int r = 0; r < 4; ++r) {
      long m = m0 + wm * 64 + mi * 16 + (lane >> 4) * 4 + r;
      float sm = scale[m];
      float* outrow = out + m * N;
      const float* auxrow = aux ? aux + m * N : nullptr;
#pragma unroll
      for (int ni = 0; ni < 4; ++ni) {
        long n = n0 + wn * 64 + ni * 16 + (lane & 15);
        float v = sm * (float)acc[mi][ni][r];
        if (mode == 0) {
          outrow[n] = auxrow[n] + v;
        } else {
          outrow[n] = 0.5f * v * (1.f + erff(v * 0.70710678118654752f));
        }
      }
    }
  }
}

extern "C" void kernel_launch(void* const* d_in, const int* in_sizes, int n_in,
                              void* d_out, int out_size, void* d_ws, size_t ws_size,
                              hipStream_t stream) {
  const float* x    = (const float*)d_in[0];
  const float* ln1w = (const float*)d_in[1];
  const float* ln1b = (const float*)d_in[2];
  const float* ln2w = (const float*)d_in[3];
  const float* ln2b = (const float*)d_in[4];
  const float* Wg   = (const float*)d_in[5];
  const float* W1   = (const float*)d_in[6];
  const float* W2   = (const float*)d_in[7];
  const int* is0    = (const int*)d_in[8];
  const int* is1    = (const int*)d_in[9];
  const int* iv     = (const int*)d_in[10];
  float* out = (float*)d_out;

  // workspace layout (all 256B-aligned, ~224 MB):
  char* ws = (char*)d_ws;
  float* sums = (float*)ws;                                   // 3 floats (+pad)
  signed char* t_g = (signed char*)(ws + 256);                // 15,728,640
  signed char* t_1 = t_g + 15728640;                          //  4,194,304
  signed char* t_2 = t_1 + 4194304;                           //  4,194,304
  float* rowmax1 = (float*)(t_2 + 4194304);                   // 32,768 B
  float* xs1 = rowmax1 + 8192;
  float* s1  = xs1 + 8192;
  float* s2  = s1 + 8192;
  float* s3  = s2 + 8192;
  float* xag = s3 + 8192;                                     // 33,554,432 B
  signed char* hq = (signed char*)(xag + 8388608);            //  8,388,608 B
  float* xn = (float*)(hq + 8388608);                         // 33,554,432 B
  signed char* q3 = (signed char*)xn;                         // reuse (xn dead after quantA)
  signed char* Aq = (signed char*)(xn + 8388608);             // 125.8 MB
  float* gg = (float*)Aq;                                     // reuse as 134.2 MB (Aq dead after GEMM1)

  hipMemsetAsync(sums, 0, 64, stream);
  absum_kernel<<<512, 256, 0, stream>>>(Wg, 15728640 / 4, &sums[0]);
  absum_kernel<<<256, 256, 0, stream>>>(W1, 4194304 / 4, &sums[1]);
  absum_kernel<<<256, 256, 0, stream>>>(W2, 4194304 / 4, &sums[2]);
  ternarize_kernel<<<1024, 256, 0, stream>>>(Wg, t_g, 15728640 / 4, &sums[0], 1.f / 15728640.f);
  ternarize_kernel<<<512, 256, 0, stream>>>(W1, t_1, 4194304 / 4, &sums[1], 1.f / 4194304.f);
  ternarize_kernel<<<512, 256, 0, stream>>>(W2, t_2, 4194304 / 4, &sums[2], 1.f / 4194304.f);
  ln_rowmax_kernel<<<8192, 256, 0, stream>>>(x, ln1w, ln1b, xn, rowmax1);
  scale1_kernel<<<32, 256, 0, stream>>>(rowmax1, is0, is1, iv, sums, xs1, s1);
  quantA_kernel<<<dim3(15, 8192), 256, 0, stream>>>(xn, is0, is1, iv, xs1, Aq);
  gemm_i8<<<dim3(8, 64), 256, 0, stream>>>(Aq, t_g, xag, s1, x, 1024, 15360, 0);
  ln_quant_kernel<<<8192, 256, 0, stream>>>(xag, ln2w, ln2b, hq, s2, &sums[1], 1.f / 4194304.f);
  gemm_i8<<<dim3(32, 64), 256, 0, stream>>>(hq, t_1, gg, s2, nullptr, 4096, 1024, 1);
  rowquant4k_kernel<<<8192, 256, 0, stream>>>(gg, q3, s3, &sums[2], 1.f / 4194304.f);
  gemm_i8<<<dim3(8, 64), 256, 0, stream>>>(q3, t_2, out, s3, xag, 1024, 4096, 0);
}

// Round 3
// 659.366 us; speedup vs baseline: 1.0932x; 1.0339x over previous
//
#include <hip/hip_runtime.h>
#include <math.h>
#include <stdint.h>

#define EPS 1e-5f

typedef int v4i __attribute__((ext_vector_type(4)));

__device__ __forceinline__ void glds16(const void* g, void* l) {
  __builtin_amdgcn_global_load_lds(
      (const __attribute__((address_space(1))) void*)g,
      (__attribute__((address_space(3))) void*)l, 16, 0, 0);
}

__device__ __forceinline__ signed char q8(float f, float xs) {
  float r = rintf(f * xs);
  r = fminf(fmaxf(r, -128.f), 127.f);
  return (signed char)(int)r;
}

// ---------------- weight abs-sum (hierarchical, 1 atomic/block) ----------------
__global__ __launch_bounds__(256) void absum_kernel(const float* __restrict__ w,
                                                    long n4, float* __restrict__ out) {
  long i = (long)blockIdx.x * 256 + threadIdx.x;
  long stride = (long)gridDim.x * 256;
  const float4* w4 = (const float4*)w;
  float s = 0.f;
  for (; i < n4; i += stride) {
    float4 v = w4[i];
    s += fabsf(v.x) + fabsf(v.y) + fabsf(v.z) + fabsf(v.w);
  }
  for (int off = 32; off; off >>= 1) s += __shfl_down(s, off);
  __shared__ float sb[4];
  int lane = threadIdx.x & 63, wid = threadIdx.x >> 6;
  if (lane == 0) sb[wid] = s;
  __syncthreads();
  if (threadIdx.x == 0) atomicAdd(out, sb[0] + sb[1] + sb[2] + sb[3]);
}

// ---------------- ternarize weights: t = clip(round(w/ws),-1,1) int8 ----------------
__global__ __launch_bounds__(256) void ternarize_kernel(const float* __restrict__ w,
                                                        signed char* __restrict__ t, long n4,
                                                        const float* __restrict__ sum_ptr,
                                                        float inv_n) {
  float ws = sum_ptr[0] * inv_n + EPS;
  long i = (long)blockIdx.x * 256 + threadIdx.x;
  long stride = (long)gridDim.x * 256;
  const float4* w4 = (const float4*)w;
  char4* t4 = (char4*)t;
  for (; i < n4; i += stride) {
    float4 v = w4[i];
    char4 c;
    c.x = (signed char)(int)fminf(fmaxf(rintf(v.x / ws), -1.f), 1.f);
    c.y = (signed char)(int)fminf(fmaxf(rintf(v.y / ws), -1.f), 1.f);
    c.z = (signed char)(int)fminf(fmaxf(rintf(v.z / ws), -1.f), 1.f);
    c.w = (signed char)(int)fminf(fmaxf(rintf(v.w / ws), -1.f), 1.f);
    t4[i] = c;
  }
}

// ---------------- LN1: write xn fp32 + per-row absmax ----------------
__global__ __launch_bounds__(256) void ln_rowmax_kernel(const float* __restrict__ x,
                                                        const float* __restrict__ w,
                                                        const float* __restrict__ b,
                                                        float* __restrict__ xn,
                                                        float* __restrict__ rowmax) {
  int m = blockIdx.x;
  int tid = threadIdx.x, lane = tid & 63, wid = tid >> 6;
  __shared__ float sb[4];
  float4 v = ((const float4*)(x + (long)m * 1024))[tid];
  float s = v.x + v.y + v.z + v.w;
  for (int off = 32; off; off >>= 1) s += __shfl_down(s, off);
  if (lane == 0) sb[wid] = s;
  __syncthreads();
  float mean = (sb[0] + sb[1] + sb[2] + sb[3]) * (1.f / 1024.f);
  __syncthreads();
  float dx = v.x - mean, dy = v.y - mean, dz = v.z - mean, dw = v.w - mean;
  float ss = dx * dx + dy * dy + dz * dz + dw * dw;
  for (int off = 32; off; off >>= 1) ss += __shfl_down(ss, off);
  if (lane == 0) sb[wid] = ss;
  __syncthreads();
  float rstd = rsqrtf((sb[0] + sb[1] + sb[2] + sb[3]) * (1.f / 1024.f) + EPS);
  __syncthreads();
  float4 wv = ((const float4*)w)[tid];
  float4 bv = ((const float4*)b)[tid];
  float4 o;
  o.x = dx * rstd * wv.x + bv.x;
  o.y = dy * rstd * wv.y + bv.y;
  o.z = dz * rstd * wv.z + bv.z;
  o.w = dw * rstd * wv.w + bv.w;
  ((float4*)(xn + (long)m * 1024))[tid] = o;
  float mx = fmaxf(fmaxf(fabsf(o.x), fabsf(o.y)), fmaxf(fabsf(o.z), fabsf(o.w)));
  for (int off = 32; off; off >>= 1) mx = fmaxf(mx, __shfl_down(mx, off));
  if (lane == 0) sb[wid] = mx;
  __syncthreads();
  if (tid == 0) rowmax[m] = fmaxf(fmaxf(sb[0], sb[1]), fmaxf(sb[2], sb[3]));
}

// ---------------- per-token combined scale ----------------
__global__ __launch_bounds__(256) void scale1_kernel(const float* __restrict__ rowmax,
                                                     const int* __restrict__ is0,
                                                     const int* __restrict__ is1,
                                                     const int* __restrict__ iv,
                                                     const float* __restrict__ sums,
                                                     float* __restrict__ xs1,
                                                     float* __restrict__ s1) {
  int t = blockIdx.x * 256 + threadIdx.x;
  if (t >= 8192) return;
  int b = t >> 8, l = t & 255;
  const float* rm = rowmax + b * 256;
  float c = rm[l];
  for (int j = 0; j < 3; ++j) c = fmaxf(c, rm[is0[l * 3 + j]]);
  for (int j = 0; j < 3; ++j) c = fmaxf(c, rm[is1[l * 3 + j]]);
  for (int j = 0; j < 8; ++j) c = fmaxf(c, rm[iv[l * 8 + j]]);
  c = fmaxf(c, EPS);
  xs1[t] = 127.f / c;
  s1[t] = (sums[0] * (1.f / 15728640.f) + EPS) * c * (1.f / 127.f);
}

// ---------------- quantize gathered combined matrix to int8 [8192,15360] ----------------
__global__ __launch_bounds__(256) void quantA_kernel(const float* __restrict__ xn,
                                                     const int* __restrict__ is0,
                                                     const int* __restrict__ is1,
                                                     const int* __restrict__ iv,
                                                     const float* __restrict__ xs1,
                                                     signed char* __restrict__ Aq) {
  int slot = blockIdx.x;  // 0..14
  int m = blockIdx.y;     // 0..8191
  int b = m >> 8, l = m & 255;
  int src;
  if (slot == 0) src = l;
  else if (slot < 4) src = is0[l * 3 + slot - 1];
  else if (slot < 7) src = is1[l * 3 + slot - 4];
  else src = iv[l * 8 + slot - 7];
  float xs = xs1[m];
  float4 v = ((const float4*)(xn + ((long)b * 256 + src) * 1024))[threadIdx.x];
  char4 c;
  c.x = q8(v.x, xs); c.y = q8(v.y, xs); c.z = q8(v.z, xs); c.w = q8(v.w, xs);
  *(char4*)&Aq[(long)m * 15360 + slot * 1024 + threadIdx.x * 4] = c;
}

// ---------------- fused: xag = x + s1*acc; LN2; quantize to int8 ----------------
__global__ __launch_bounds__(256) void ln_quant_acc_kernel(const int* __restrict__ acc,
                                                           const float* __restrict__ x,
                                                           const float* __restrict__ s1,
                                                           const float* __restrict__ w,
                                                           const float* __restrict__ bb,
                                                           float* __restrict__ xag,
                                                           signed char* __restrict__ q,
                                                           float* __restrict__ srow,
                                                           const float* __restrict__ sum_ptr,
                                                           float inv_n) {
  int m = blockIdx.x;
  int tid = threadIdx.x, lane = tid & 63, wid = tid >> 6;
  __shared__ float sb[4];
  float sm = s1[m];
  int4 a = ((const int4*)(acc + (long)m * 1024))[tid];
  float4 xv = ((const float4*)(x + (long)m * 1024))[tid];
  float4 v;
  v.x = xv.x + sm * (float)a.x;
  v.y = xv.y + sm * (float)a.y;
  v.z = xv.z + sm * (float)a.z;
  v.w = xv.w + sm * (float)a.w;
  ((float4*)(xag + (long)m * 1024))[tid] = v;
  float s = v.x + v.y + v.z + v.w;
  for (int off = 32; off; off >>= 1) s += __shfl_down(s, off);
  if (lane == 0) sb[wid] = s;
  __syncthreads();
  float mean = (sb[0] + sb[1] + sb[2] + sb[3]) * (1.f / 1024.f);
  __syncthreads();
  float dx = v.x - mean, dy = v.y - mean, dz = v.z - mean, dw = v.w - mean;
  float ss = dx * dx + dy * dy + dz * dz + dw * dw;
  for (int off = 32; off; off >>= 1) ss += __shfl_down(ss, off);
  if (lane == 0) sb[wid] = ss;
  __syncthreads();
  float rstd = rsqrtf((sb[0] + sb[1] + sb[2] + sb[3]) * (1.f / 1024.f) + EPS);
  __syncthreads();
  float4 wv = ((const float4*)w)[tid];
  float4 bv = ((const float4*)bb)[tid];
  float nx = dx * rstd * wv.x + bv.x;
  float ny = dy * rstd * wv.y + bv.y;
  float nz = dz * rstd * wv.z + bv.z;
  float nw = dw * rstd * wv.w + bv.w;
  float mx = fmaxf(fmaxf(fabsf(nx), fabsf(ny)), fmaxf(fabsf(nz), fabsf(nw)));
  for (int off = 32; off; off >>= 1) mx = fmaxf(mx, __shfl_down(mx, off));
  if (lane == 0) sb[wid] = mx;
  __syncthreads();
  float rmax = fmaxf(fmaxf(fmaxf(sb[0], sb[1]), fmaxf(sb[2], sb[3])), EPS);
  float xs = 127.f / rmax;
  char4 c;
  c.x = q8(nx, xs); c.y = q8(ny, xs); c.z = q8(nz, xs); c.w = q8(nw, xs);
  *(char4*)&q[(long)m * 1024 + tid * 4] = c;
  if (tid == 0) srow[m] = (sum_ptr[0] * inv_n + EPS) * rmax * (1.f / 127.f);
}

// ---------------- row quantize [8192,4096] fp32 -> int8 ----------------
__global__ __launch_bounds__(256) void rowquant4k_kernel(const float* __restrict__ g,
                                                         signed char* __restrict__ q,
                                                         float* __restrict__ srow,
                                                         const float* __restrict__ sum_ptr,
                                                         float inv_n) {
  int m = blockIdx.x;
  int tid = threadIdx.x, lane = tid & 63, wid = tid >> 6;
  __shared__ float sb[4];
  const float4* gr = (const float4*)(g + (long)m * 4096);
  float4 vals[4];
  float mx = 0.f;
#pragma unroll
  for (int i = 0; i < 4; ++i) {
    vals[i] = gr[tid + i * 256];
    mx = fmaxf(mx, fmaxf(fmaxf(fabsf(vals[i].x), fabsf(vals[i].y)),
                         fmaxf(fabsf(vals[i].z), fabsf(vals[i].w))));
  }
  for (int off = 32; off; off >>= 1) mx = fmaxf(mx, __shfl_down(mx, off));
  if (lane == 0) sb[wid] = mx;
  __syncthreads();
  float rmax = fmaxf(fmaxf(fmaxf(sb[0], sb[1]), fmaxf(sb[2], sb[3])), EPS);
  float xs = 127.f / rmax;
#pragma unroll
  for (int i = 0; i < 4; ++i) {
    char4 c;
    c.x = q8(vals[i].x, xs); c.y = q8(vals[i].y, xs);
    c.z = q8(vals[i].z, xs); c.w = q8(vals[i].w, xs);
    *(char4*)&q[(long)m * 4096 + (tid + i * 256) * 4] = c;
  }
  if (tid == 0) srow[m] = (sum_ptr[0] * inv_n + EPS) * rmax * (1.f / 127.f);
}

// ---------------- final residual: out = xag + s3*acc ----------------
__global__ __launch_bounds__(256) void reduce3_kernel(const int* __restrict__ acc,
                                                      const float* __restrict__ xag,
                                                      const float* __restrict__ s3,
                                                      float* __restrict__ out) {
  int m = blockIdx.x;
  float sm = s3[m];
  int4 a = ((const int4*)(acc + (long)m * 1024))[threadIdx.x];
  float4 xv = ((const float4*)(xag + (long)m * 1024))[threadIdx.x];
  float4 o;
  o.x = xv.x + sm * (float)a.x;
  o.y = xv.y + sm * (float)a.y;
  o.z = xv.z + sm * (float)a.z;
  o.w = xv.w + sm * (float)a.w;
  ((float4*)(out + (long)m * 1024))[threadIdx.x] = o;
}

// ---------------- int8 GEMM, 128x128 tile, BK=128, 16x16x64 MFMA, split-K ----------------
// XOR-swizzled LDS (r1: bank conflicts = 0). blockIdx.z = K-split; each split
// covers kIters*128 of K. A: [M,K] i8 row-major; Bw: [N,K] i8 row-major.
// mode 0: out[m,n] = aux[m,n] + scale[m]*acc (fp32)
// mode 1: out[m,n] = gelu(scale[m]*acc)      (fp32)
// mode 2: atomicAdd(&iacc[m*N+n], acc)       (exact i32 split-K reduction)
__global__ __launch_bounds__(256, 4) void gemm_i8(const signed char* __restrict__ A,
                                                  const signed char* __restrict__ Bw,
                                                  float* __restrict__ out,
                                                  int* __restrict__ iacc,
                                                  const float* __restrict__ scale,
                                                  const float* __restrict__ aux,
                                                  int N, int K, int kIters, int mode) {
  __shared__ __align__(16) signed char As[128 * 128];
  __shared__ __align__(16) signed char Bs[128 * 128];
  const int tid = threadIdx.x;
  const int lane = tid & 63, wave = tid >> 6;
  const int wm = wave & 1, wn = wave >> 1;
  const long m0 = (long)blockIdx.y * 128;
  const long n0 = (long)blockIdx.x * 128;
  const signed char* Abase = A + m0 * K;
  const signed char* Bbase = Bw + n0 * K;

  v4i acc[4][4] = {};

  const int r15 = lane & 15;
  const int quad = lane >> 4;   // 0..3
  const int sw = lane & 7;      // = row&7 for all fragment rows

  for (int kt = 0; kt < kIters; ++kt) {
    const long k0 = ((long)blockIdx.z * kIters + kt) << 7;
#pragma unroll
    for (int i = 0; i < 4; ++i) {
      int cb = wave * 64 + i * 256;        // wave-uniform chunk base
      int c = cb + lane;                   // per-lane chunk
      long row = c >> 3;
      int blk = (c & 7) ^ ((c >> 3) & 7);  // XOR swizzle of source block
      long colb = (long)blk << 4;
      glds16(Abase + row * K + k0 + colb, &As[cb * 16]);
      glds16(Bbase + row * K + k0 + colb, &Bs[cb * 16]);
    }
    __syncthreads();
#pragma unroll
    for (int ks = 0; ks < 2; ++ks) {
      const int blkb = (ks << 2) + quad;   // logical 16B block index (0..7)
      const int coff = (blkb ^ sw) << 4;   // swizzled byte offset within row
      v4i af[4], bf[4];
#pragma unroll
      for (int mi = 0; mi < 4; ++mi)
        af[mi] = *(const v4i*)&As[(wm * 64 + mi * 16 + r15) * 128 + coff];
#pragma unroll
      for (int ni = 0; ni < 4; ++ni)
        bf[ni] = *(const v4i*)&Bs[(wn * 64 + ni * 16 + r15) * 128 + coff];
#pragma unroll
      for (int mi = 0; mi < 4; ++mi)
#pragma unroll
        for (int ni = 0; ni < 4; ++ni)
          acc[mi][ni] = __builtin_amdgcn_mfma_i32_16x16x64_i8(af[mi], bf[ni], acc[mi][ni], 0, 0, 0);
    }
    __syncthreads();
  }

  // epilogue: C/D layout col=lane&15, row=(lane>>4)*4+reg
#pragma unroll
  for (int mi = 0; mi < 4; ++mi) {
#pragma unroll
    for (int r = 0; r < 4; ++r) {
      long m = m0 + wm * 64 + mi * 16 + (lane >> 4) * 4 + r;
      if (mode == 2) {
        int* arow = iacc + m * N;
#pragma unroll
        for (int ni = 0; ni < 4; ++ni) {
          long n = n0 + wn * 64 + ni * 16 + (lane & 15);
          atomicAdd(&arow[n], acc[mi][ni][r]);
        }
      } else {
        float sm = scale[m];
        float* outrow = out + m * N;
        const float* auxrow = aux ? aux + m * N : nullptr;
#pragma unroll
        for (int ni = 0; ni < 4; ++ni) {
          long n = n0 + wn * 64 + ni * 16 + (lane & 15);
          float v = sm * (float)acc[mi][ni][r];
          if (mode == 0) {
            outrow[n] = auxrow[n] + v;
          } else {
            outrow[n] = 0.5f * v * (1.f + erff(v * 0.70710678118654752f));
          }
        }
      }
    }
  }
}

extern "C" void kernel_launch(void* const* d_in, const int* in_sizes, int n_in,
                              void* d_out, int out_size, void* d_ws, size_t ws_size,
                              hipStream_t stream) {
  const float* x    = (const float*)d_in[0];
  const float* ln1w = (const float*)d_in[1];
  const float* ln1b = (const float*)d_in[2];
  const float* ln2w = (const float*)d_in[3];
  const float* ln2b = (const float*)d_in[4];
  const float* Wg   = (const float*)d_in[5];
  const float* W1   = (const float*)d_in[6];
  const float* W2   = (const float*)d_in[7];
  const int* is0    = (const int*)d_in[8];
  const int* is1    = (const int*)d_in[9];
  const int* iv     = (const int*)d_in[10];
  float* out = (float*)d_out;

  // workspace layout (peak ~224 MiB, same as r1 which passed):
  char* ws = (char*)d_ws;
  float* sums = (float*)ws;                                   // 3 floats (+pad)
  signed char* t_g = (signed char*)(ws + 256);                // 15,728,640
  signed char* t_1 = t_g + 15728640;                          //  4,194,304
  signed char* t_2 = t_1 + 4194304;                           //  4,194,304
  float* rowmax1 = (float*)(t_2 + 4194304);                   // 32,768 B
  float* xs1 = rowmax1 + 8192;
  float* s1  = xs1 + 8192;
  float* s2  = s1 + 8192;
  float* s3  = s2 + 8192;
  float* xag = s3 + 8192;                                     // 33.55 MB (alive to end)
  signed char* hq = (signed char*)(xag + 8388608);            //  8.39 MB
  // region H (33.55 MB): xn -> acc1 -> q3 (sequential lifetimes)
  float* xn = (float*)(hq + 8388608);
  int* acc1 = (int*)xn;
  signed char* q3 = (signed char*)xn;
  // region I (134.2 MB): Aq -> gg -> acc3 (sequential lifetimes)
  signed char* Aq = (signed char*)(xn + 8388608);
  float* gg = (float*)Aq;
  int* acc3 = (int*)Aq;

  hipMemsetAsync(sums, 0, 64, stream);
  absum_kernel<<<512, 256, 0, stream>>>(Wg, 15728640 / 4, &sums[0]);
  absum_kernel<<<256, 256, 0, stream>>>(W1, 4194304 / 4, &sums[1]);
  absum_kernel<<<256, 256, 0, stream>>>(W2, 4194304 / 4, &sums[2]);
  ternarize_kernel<<<1024, 256, 0, stream>>>(Wg, t_g, 15728640 / 4, &sums[0], 1.f / 15728640.f);
  ternarize_kernel<<<512, 256, 0, stream>>>(W1, t_1, 4194304 / 4, &sums[1], 1.f / 4194304.f);
  ternarize_kernel<<<512, 256, 0, stream>>>(W2, t_2, 4194304 / 4, &sums[2], 1.f / 4194304.f);
  ln_rowmax_kernel<<<8192, 256, 0, stream>>>(x, ln1w, ln1b, xn, rowmax1);
  scale1_kernel<<<32, 256, 0, stream>>>(rowmax1, is0, is1, iv, sums, xs1, s1);
  quantA_kernel<<<dim3(15, 8192), 256, 0, stream>>>(xn, is0, is1, iv, xs1, Aq);
  // GEMM1: M=8192 N=1024 K=15360, split-K=2 -> 1024 blocks (4/CU)
  hipMemsetAsync(acc1, 0, 8192l * 1024 * 4, stream);
  gemm_i8<<<dim3(8, 64, 2), 256, 0, stream>>>(Aq, t_g, nullptr, acc1, nullptr, nullptr,
                                              1024, 15360, 60, 2);
  ln_quant_acc_kernel<<<8192, 256, 0, stream>>>(acc1, x, s1, ln2w, ln2b, xag, hq, s2,
                                                &sums[1], 1.f / 4194304.f);
  // GEMM2: M=8192 N=4096 K=1024 -> 2048 blocks already
  gemm_i8<<<dim3(32, 64, 1), 256, 0, stream>>>(hq, t_1, gg, nullptr, s2, nullptr,
                                               4096, 1024, 8, 1);
  rowquant4k_kernel<<<8192, 256, 0, stream>>>(gg, q3, s3, &sums[2], 1.f / 4194304.f);
  // GEMM3: M=8192 N=1024 K=4096, split-K=2 -> 1024 blocks (4/CU)
  hipMemsetAsync(acc3, 0, 8192l * 1024 * 4, stream);
  gemm_i8<<<dim3(8, 64, 2), 256, 0, stream>>>(q3, t_2, nullptr, acc3, nullptr, nullptr,
                                              1024, 4096, 16, 2);
  reduce3_kernel<<<8192, 256, 0, stream>>>(acc3, xag, s3, out);
}

// Round 4
// 559.204 us; speedup vs baseline: 1.2890x; 1.1791x over previous
//
#include <hip/hip_runtime.h>
#include <hip/hip_bf16.h>
#include <math.h>
#include <stdint.h>

#define EPS 1e-5f

typedef int v4i __attribute__((ext_vector_type(4)));

__device__ __forceinline__ void glds16(const void* g, void* l) {
  __builtin_amdgcn_global_load_lds(
      (const __attribute__((address_space(1))) void*)g,
      (__attribute__((address_space(3))) void*)l, 16, 0, 0);
}

__device__ __forceinline__ signed char q8(float f, float xs) {
  float r = rintf(f * xs);
  r = fminf(fmaxf(r, -128.f), 127.f);
  return (signed char)(int)r;
}

__device__ __forceinline__ float bf2f(unsigned short h) {
  return __builtin_bit_cast(float, (unsigned)h << 16);
}

// ---------------- merged weight abs-sum (3 tensors, 1 launch) ----------------
__global__ __launch_bounds__(256) void absum3_kernel(const float* __restrict__ Wg,
                                                     const float* __restrict__ W1,
                                                     const float* __restrict__ W2,
                                                     float* __restrict__ out) {
  int blk = blockIdx.x;
  const float* w; long n4; float* o; long lb; long nb;
  if (blk < 512)      { w = Wg; n4 = 3932160; o = &out[0]; lb = blk;       nb = 512; }
  else if (blk < 768) { w = W1; n4 = 1048576; o = &out[1]; lb = blk - 512; nb = 256; }
  else                { w = W2; n4 = 1048576; o = &out[2]; lb = blk - 768; nb = 256; }
  const float4* w4 = (const float4*)w;
  float s = 0.f;
  for (long i = lb * 256 + threadIdx.x; i < n4; i += nb * 256) {
    float4 v = w4[i];
    s += fabsf(v.x) + fabsf(v.y) + fabsf(v.z) + fabsf(v.w);
  }
  for (int off = 32; off; off >>= 1) s += __shfl_down(s, off);
  __shared__ float sb[4];
  int lane = threadIdx.x & 63, wid = threadIdx.x >> 6;
  if (lane == 0) sb[wid] = s;
  __syncthreads();
  if (threadIdx.x == 0) atomicAdd(o, sb[0] + sb[1] + sb[2] + sb[3]);
}

// ---------------- merged ternarize (3 tensors, 1 launch) ----------------
__global__ __launch_bounds__(256) void ternarize3_kernel(const float* __restrict__ Wg,
                                                         const float* __restrict__ W1,
                                                         const float* __restrict__ W2,
                                                         signed char* __restrict__ tg,
                                                         signed char* __restrict__ t1,
                                                         signed char* __restrict__ t2,
                                                         const float* __restrict__ sums) {
  int blk = blockIdx.x;
  const float* w; signed char* t; long n4; float ws; long lb; long nb;
  if (blk < 1024) {
    w = Wg; t = tg; n4 = 3932160; ws = sums[0] * (1.f / 15728640.f) + EPS; lb = blk; nb = 1024;
  } else if (blk < 1536) {
    w = W1; t = t1; n4 = 1048576; ws = sums[1] * (1.f / 4194304.f) + EPS; lb = blk - 1024; nb = 512;
  } else {
    w = W2; t = t2; n4 = 1048576; ws = sums[2] * (1.f / 4194304.f) + EPS; lb = blk - 1536; nb = 512;
  }
  const float4* w4 = (const float4*)w;
  char4* t4 = (char4*)t;
  for (long i = lb * 256 + threadIdx.x; i < n4; i += nb * 256) {
    float4 v = w4[i];
    char4 c;
    c.x = (signed char)(int)fminf(fmaxf(rintf(v.x / ws), -1.f), 1.f);
    c.y = (signed char)(int)fminf(fmaxf(rintf(v.y / ws), -1.f), 1.f);
    c.z = (signed char)(int)fminf(fmaxf(rintf(v.z / ws), -1.f), 1.f);
    c.w = (signed char)(int)fminf(fmaxf(rintf(v.w / ws), -1.f), 1.f);
    t4[i] = c;
  }
}

// ---------------- LN1: write xn fp32 + per-row absmax ----------------
__global__ __launch_bounds__(256) void ln_rowmax_kernel(const float* __restrict__ x,
                                                        const float* __restrict__ w,
                                                        const float* __restrict__ b,
                                                        float* __restrict__ xn,
                                                        float* __restrict__ rowmax) {
  int m = blockIdx.x;
  int tid = threadIdx.x, lane = tid & 63, wid = tid >> 6;
  __shared__ float sb[4];
  float4 v = ((const float4*)(x + (long)m * 1024))[tid];
  float s = v.x + v.y + v.z + v.w;
  for (int off = 32; off; off >>= 1) s += __shfl_down(s, off);
  if (lane == 0) sb[wid] = s;
  __syncthreads();
  float mean = (sb[0] + sb[1] + sb[2] + sb[3]) * (1.f / 1024.f);
  __syncthreads();
  float dx = v.x - mean, dy = v.y - mean, dz = v.z - mean, dw = v.w - mean;
  float ss = dx * dx + dy * dy + dz * dz + dw * dw;
  for (int off = 32; off; off >>= 1) ss += __shfl_down(ss, off);
  if (lane == 0) sb[wid] = ss;
  __syncthreads();
  float rstd = rsqrtf((sb[0] + sb[1] + sb[2] + sb[3]) * (1.f / 1024.f) + EPS);
  __syncthreads();
  float4 wv = ((const float4*)w)[tid];
  float4 bv = ((const float4*)b)[tid];
  float4 o;
  o.x = dx * rstd * wv.x + bv.x;
  o.y = dy * rstd * wv.y + bv.y;
  o.z = dz * rstd * wv.z + bv.z;
  o.w = dw * rstd * wv.w + bv.w;
  ((float4*)(xn + (long)m * 1024))[tid] = o;
  float mx = fmaxf(fmaxf(fabsf(o.x), fabsf(o.y)), fmaxf(fabsf(o.z), fabsf(o.w)));
  for (int off = 32; off; off >>= 1) mx = fmaxf(mx, __shfl_down(mx, off));
  if (lane == 0) sb[wid] = mx;
  __syncthreads();
  if (tid == 0) rowmax[m] = fmaxf(fmaxf(sb[0], sb[1]), fmaxf(sb[2], sb[3]));
}

// ---------------- quantA: per-dest-row combined scale + gather-quantize ----------------
// One block per destination row m; computes cmax/scale inline (kills scale1 kernel).
__global__ __launch_bounds__(256) void quantA_kernel(const float* __restrict__ xn,
                                                     const int* __restrict__ is0,
                                                     const int* __restrict__ is1,
                                                     const int* __restrict__ iv,
                                                     const float* __restrict__ rowmax,
                                                     const float* __restrict__ sums,
                                                     signed char* __restrict__ Aq,
                                                     float* __restrict__ s1) {
  int m = blockIdx.x;
  int b = m >> 8, l = m & 255;
  const float* rm = rowmax + b * 256;
  int src[15];
  src[0] = l;
#pragma unroll
  for (int j = 0; j < 3; ++j) { src[1 + j] = is0[l * 3 + j]; src[4 + j] = is1[l * 3 + j]; }
#pragma unroll
  for (int j = 0; j < 8; ++j) src[7 + j] = iv[l * 8 + j];
  float c = EPS;
#pragma unroll
  for (int sl = 0; sl < 15; ++sl) c = fmaxf(c, rm[src[sl]]);
  float xs = 127.f / c;
  if (threadIdx.x == 0) s1[m] = (sums[0] * (1.f / 15728640.f) + EPS) * c * (1.f / 127.f);
#pragma unroll
  for (int sl = 0; sl < 15; ++sl) {
    float4 v = ((const float4*)(xn + ((long)(b << 8) + src[sl]) * 1024))[threadIdx.x];
    char4 cc;
    cc.x = q8(v.x, xs); cc.y = q8(v.y, xs); cc.z = q8(v.z, xs); cc.w = q8(v.w, xs);
    *(char4*)&Aq[(long)m * 15360 + sl * 1024 + threadIdx.x * 4] = cc;
  }
}

// ---------------- fused: xag = x + s1*(acc0+acc1); LN2; quantize to int8 ----------------
// NOTE: accB may alias xag (identical base); safe: per-thread identity addresses,
// store data-depends on the load. No __restrict__ on accB/xag.
__global__ __launch_bounds__(256) void ln_quant_acc_kernel(const int* __restrict__ accA,
                                                           const int* accB,
                                                           const float* __restrict__ x,
                                                           const float* __restrict__ s1,
                                                           const float* __restrict__ w,
                                                           const float* __restrict__ bb,
                                                           float* xag,
                                                           signed char* __restrict__ q,
                                                           float* __restrict__ srow,
                                                           const float* __restrict__ sum_ptr,
                                                           float inv_n) {
  int m = blockIdx.x;
  int tid = threadIdx.x, lane = tid & 63, wid = tid >> 6;
  __shared__ float sb[4];
  float sm = s1[m];
  int4 a0 = ((const int4*)(accA + (long)m * 1024))[tid];
  int4 a1 = ((const int4*)(accB + (long)m * 1024))[tid];
  float4 xv = ((const float4*)(x + (long)m * 1024))[tid];
  float4 v;
  v.x = xv.x + sm * (float)(a0.x + a1.x);
  v.y = xv.y + sm * (float)(a0.y + a1.y);
  v.z = xv.z + sm * (float)(a0.z + a1.z);
  v.w = xv.w + sm * (float)(a0.w + a1.w);
  ((float4*)(xag + (long)m * 1024))[tid] = v;
  float s = v.x + v.y + v.z + v.w;
  for (int off = 32; off; off >>= 1) s += __shfl_down(s, off);
  if (lane == 0) sb[wid] = s;
  __syncthreads();
  float mean = (sb[0] + sb[1] + sb[2] + sb[3]) * (1.f / 1024.f);
  __syncthreads();
  float dx = v.x - mean, dy = v.y - mean, dz = v.z - mean, dw = v.w - mean;
  float ss = dx * dx + dy * dy + dz * dz + dw * dw;
  for (int off = 32; off; off >>= 1) ss += __shfl_down(ss, off);
  if (lane == 0) sb[wid] = ss;
  __syncthreads();
  float rstd = rsqrtf((sb[0] + sb[1] + sb[2] + sb[3]) * (1.f / 1024.f) + EPS);
  __syncthreads();
  float4 wv = ((const float4*)w)[tid];
  float4 bv = ((const float4*)bb)[tid];
  float nx = dx * rstd * wv.x + bv.x;
  float ny = dy * rstd * wv.y + bv.y;
  float nz = dz * rstd * wv.z + bv.z;
  float nw = dw * rstd * wv.w + bv.w;
  float mx = fmaxf(fmaxf(fabsf(nx), fabsf(ny)), fmaxf(fabsf(nz), fabsf(nw)));
  for (int off = 32; off; off >>= 1) mx = fmaxf(mx, __shfl_down(mx, off));
  if (lane == 0) sb[wid] = mx;
  __syncthreads();
  float rmax = fmaxf(fmaxf(fmaxf(sb[0], sb[1]), fmaxf(sb[2], sb[3])), EPS);
  float xs = 127.f / rmax;
  char4 c;
  c.x = q8(nx, xs); c.y = q8(ny, xs); c.z = q8(nz, xs); c.w = q8(nw, xs);
  *(char4*)&q[(long)m * 1024 + tid * 4] = c;
  if (tid == 0) srow[m] = (sum_ptr[0] * inv_n + EPS) * rmax * (1.f / 127.f);
}

// ---------------- row quantize [8192,4096] bf16 -> int8 ----------------
__global__ __launch_bounds__(256) void rowquant4k_kernel(const unsigned short* __restrict__ g,
                                                         signed char* __restrict__ q,
                                                         float* __restrict__ srow,
                                                         const float* __restrict__ sum_ptr,
                                                         float inv_n) {
  int m = blockIdx.x;
  int tid = threadIdx.x, lane = tid & 63, wid = tid >> 6;
  __shared__ float sb[4];
  const uint4* gr = (const uint4*)(g + (long)m * 4096);  // 16B = 8 bf16
  float f[16];
  float mx = 0.f;
#pragma unroll
  for (int i = 0; i < 2; ++i) {
    uint4 u = gr[tid + i * 256];
    unsigned uu[4] = {u.x, u.y, u.z, u.w};
#pragma unroll
    for (int j = 0; j < 4; ++j) {
      float lo = bf2f((unsigned short)(uu[j] & 0xFFFF));
      float hi = bf2f((unsigned short)(uu[j] >> 16));
      f[i * 8 + j * 2] = lo;
      f[i * 8 + j * 2 + 1] = hi;
      mx = fmaxf(mx, fmaxf(fabsf(lo), fabsf(hi)));
    }
  }
  for (int off = 32; off; off >>= 1) mx = fmaxf(mx, __shfl_down(mx, off));
  if (lane == 0) sb[wid] = mx;
  __syncthreads();
  float rmax = fmaxf(fmaxf(fmaxf(sb[0], sb[1]), fmaxf(sb[2], sb[3])), EPS);
  float xs = 127.f / rmax;
#pragma unroll
  for (int i = 0; i < 2; ++i) {
    char4 c0, c1;
    c0.x = q8(f[i * 8 + 0], xs); c0.y = q8(f[i * 8 + 1], xs);
    c0.z = q8(f[i * 8 + 2], xs); c0.w = q8(f[i * 8 + 3], xs);
    c1.x = q8(f[i * 8 + 4], xs); c1.y = q8(f[i * 8 + 5], xs);
    c1.z = q8(f[i * 8 + 6], xs); c1.w = q8(f[i * 8 + 7], xs);
    long base = (long)m * 4096 + (tid + i * 256) * 8;
    *(char4*)&q[base] = c0;
    *(char4*)&q[base + 4] = c1;
  }
  if (tid == 0) srow[m] = (sum_ptr[0] * inv_n + EPS) * rmax * (1.f / 127.f);
}

// ---------------- final residual: out = xag + s3*(acc0+acc1) ----------------
__global__ __launch_bounds__(256) void reduce3_kernel(const int* __restrict__ accA,
                                                      const int* __restrict__ accB,
                                                      const float* __restrict__ xag,
                                                      const float* __restrict__ s3,
                                                      float* __restrict__ out) {
  int m = blockIdx.x;
  float sm = s3[m];
  int4 a0 = ((const int4*)(accA + (long)m * 1024))[threadIdx.x];
  int4 a1 = ((const int4*)(accB + (long)m * 1024))[threadIdx.x];
  float4 xv = ((const float4*)(xag + (long)m * 1024))[threadIdx.x];
  float4 o;
  o.x = xv.x + sm * (float)(a0.x + a1.x);
  o.y = xv.y + sm * (float)(a0.y + a1.y);
  o.z = xv.z + sm * (float)(a0.z + a1.z);
  o.w = xv.w + sm * (float)(a0.w + a1.w);
  ((float4*)(out + (long)m * 1024))[threadIdx.x] = o;
}

// ---------------- int8 GEMM, 128x128 tile, BK=128, 16x16x64 MFMA, split-K ----------------
// Grid: blockIdx.x = m-tile (FASTEST -> blocks sharing a B... sharing nothing;
// the 8/32 blocks sharing an A-tile have ids congruent mod 8 -> same XCD L2).
// XOR-swizzled LDS (bank conflicts = 0, r2-verified).
// mode 1: outh[m,n] = bf16(gelu(scale[m]*acc))        (z must be 0)
// mode 2: (z ? iacc1 : iacc0)[m*N+n] = acc            (plain store, no memset needed)
__global__ __launch_bounds__(256, 4) void gemm_i8(const signed char* __restrict__ A,
                                                  const signed char* __restrict__ Bw,
                                                  __hip_bfloat16* __restrict__ outh,
                                                  int* __restrict__ iacc0,
                                                  int* __restrict__ iacc1,
                                                  const float* __restrict__ scale,
                                                  int N, int K, int kIters, int mode) {
  __shared__ __align__(16) signed char As[128 * 128];
  __shared__ __align__(16) signed char Bs[128 * 128];
  const int tid = threadIdx.x;
  const int lane = tid & 63, wave = tid >> 6;
  const int wm = wave & 1, wn = wave >> 1;
  const long m0 = (long)blockIdx.x * 128;
  const long n0 = (long)blockIdx.y * 128;
  const signed char* Abase = A + m0 * K;
  const signed char* Bbase = Bw + n0 * K;

  v4i acc[4][4] = {};

  const int r15 = lane & 15;
  const int quad = lane >> 4;
  const int sw = lane & 7;

  for (int kt = 0; kt < kIters; ++kt) {
    const long k0 = ((long)blockIdx.z * kIters + kt) << 7;
#pragma unroll
    for (int i = 0; i < 4; ++i) {
      int cb = wave * 64 + i * 256;
      int c = cb + lane;
      long row = c >> 3;
      int blk = (c & 7) ^ ((c >> 3) & 7);
      long colb = (long)blk << 4;
      glds16(Abase + row * K + k0 + colb, &As[cb * 16]);
      glds16(Bbase + row * K + k0 + colb, &Bs[cb * 16]);
    }
    __syncthreads();
#pragma unroll
    for (int ks = 0; ks < 2; ++ks) {
      const int blkb = (ks << 2) + quad;
      const int coff = (blkb ^ sw) << 4;
      v4i af[4], bf[4];
#pragma unroll
      for (int mi = 0; mi < 4; ++mi)
        af[mi] = *(const v4i*)&As[(wm * 64 + mi * 16 + r15) * 128 + coff];
#pragma unroll
      for (int ni = 0; ni < 4; ++ni)
        bf[ni] = *(const v4i*)&Bs[(wn * 64 + ni * 16 + r15) * 128 + coff];
#pragma unroll
      for (int mi = 0; mi < 4; ++mi)
#pragma unroll
        for (int ni = 0; ni < 4; ++ni)
          acc[mi][ni] = __builtin_amdgcn_mfma_i32_16x16x64_i8(af[mi], bf[ni], acc[mi][ni], 0, 0, 0);
    }
    __syncthreads();
  }

  int* iacc = blockIdx.z ? iacc1 : iacc0;
#pragma unroll
  for (int mi = 0; mi < 4; ++mi) {
#pragma unroll
    for (int r = 0; r < 4; ++r) {
      long m = m0 + wm * 64 + mi * 16 + (lane >> 4) * 4 + r;
      if (mode == 2) {
        int* arow = iacc + m * N;
#pragma unroll
        for (int ni = 0; ni < 4; ++ni) {
          long n = n0 + wn * 64 + ni * 16 + (lane & 15);
          arow[n] = acc[mi][ni][r];
        }
      } else {
        float sm = scale[m];
        __hip_bfloat16* orow = outh + m * N;
#pragma unroll
        for (int ni = 0; ni < 4; ++ni) {
          long n = n0 + wn * 64 + ni * 16 + (lane & 15);
          float v = sm * (float)acc[mi][ni][r];
          orow[n] = __float2bfloat16(0.5f * v * (1.f + erff(v * 0.70710678118654752f)));
        }
      }
    }
  }
}

extern "C" void kernel_launch(void* const* d_in, const int* in_sizes, int n_in,
                              void* d_out, int out_size, void* d_ws, size_t ws_size,
                              hipStream_t stream) {
  const float* x    = (const float*)d_in[0];
  const float* ln1w = (const float*)d_in[1];
  const float* ln1b = (const float*)d_in[2];
  const float* ln2w = (const float*)d_in[3];
  const float* ln2b = (const float*)d_in[4];
  const float* Wg   = (const float*)d_in[5];
  const float* W1   = (const float*)d_in[6];
  const float* W2   = (const float*)d_in[7];
  const int* is0    = (const int*)d_in[8];
  const int* is1    = (const int*)d_in[9];
  const int* iv     = (const int*)d_in[10];
  float* out = (float*)d_out;

  // workspace layout, peak ~234 MB (same footprint as r3 which passed):
  char* ws = (char*)d_ws;
  float* sums = (float*)ws;                                   // 3 floats (+pad)
  signed char* t_g = (signed char*)(ws + 256);                // 15,728,640
  signed char* t_1 = t_g + 15728640;                          //  4,194,304
  signed char* t_2 = t_1 + 4194304;                           //  4,194,304
  float* rowmax1 = (float*)(t_2 + 4194304);                   // 32 KB
  float* s1  = rowmax1 + 8192;
  float* s2  = s1 + 8192;
  float* s3  = s2 + 8192;
  // xag region (33.55 MB): acc1 partial-1 (32 MB) -> xag (identity alias, then alive to end)
  float* xag = s3 + 8192;
  int* acc1b = (int*)xag;
  signed char* hq = (signed char*)(xag + 8388608);            //  8.39 MB
  // region H (33.55 MB): xn -> acc1 partial-0 -> q3 (sequential lifetimes)
  float* xn = (float*)(hq + 8388608);
  int* acc1a = (int*)xn;
  signed char* q3 = (signed char*)xn;
  // region I (134.2 MB): Aq (126 MB) -> gg bf16 (67 MB) -> acc3 pair (64 MB)
  signed char* Aq = (signed char*)(xn + 8388608);
  unsigned short* gg = (unsigned short*)Aq;
  int* acc3a = (int*)Aq;
  int* acc3b = acc3a + 8192l * 1024;

  hipMemsetAsync(sums, 0, 64, stream);
  absum3_kernel<<<1024, 256, 0, stream>>>(Wg, W1, W2, sums);
  ternarize3_kernel<<<2048, 256, 0, stream>>>(Wg, W1, W2, t_g, t_1, t_2, sums);
  ln_rowmax_kernel<<<8192, 256, 0, stream>>>(x, ln1w, ln1b, xn, rowmax1);
  quantA_kernel<<<8192, 256, 0, stream>>>(xn, is0, is1, iv, rowmax1, sums, Aq, s1);
  // GEMM1: M=8192 N=1024 K=15360, split-K=2, grid (m=64 fastest, n=8, z=2)
  gemm_i8<<<dim3(64, 8, 2), 256, 0, stream>>>(Aq, t_g, nullptr, acc1a, acc1b, nullptr,
                                              1024, 15360, 60, 2);
  ln_quant_acc_kernel<<<8192, 256, 0, stream>>>(acc1a, acc1b, x, s1, ln2w, ln2b, xag, hq, s2,
                                                &sums[1], 1.f / 4194304.f);
  // GEMM2: M=8192 N=4096 K=1024, gelu -> bf16, grid (m=64, n=32)
  gemm_i8<<<dim3(64, 32, 1), 256, 0, stream>>>(hq, t_1, (__hip_bfloat16*)gg, nullptr, nullptr,
                                               s2, 4096, 1024, 8, 1);
  rowquant4k_kernel<<<8192, 256, 0, stream>>>(gg, q3, s3, &sums[2], 1.f / 4194304.f);
  // GEMM3: M=8192 N=1024 K=4096, split-K=2
  gemm_i8<<<dim3(64, 8, 2), 256, 0, stream>>>(q3, t_2, nullptr, acc3a, acc3b, nullptr,
                                              1024, 4096, 16, 2);
  reduce3_kernel<<<8192, 256, 0, stream>>>(acc3a, acc3b, xag, s3, out);
}